// Round 1
// baseline (81.921 us; speedup 1.0000x reference)
//
#include <hip/hip_runtime.h>
#include <math.h>

#define HDIM 1024
#define NH 32
#define LLEN 4096
#define LT 256   // l-values per block

__global__ __launch_bounds__(LT) void s4d_kernel(
    const float* __restrict__ C_ri,
    const float* __restrict__ log_dt,
    const float* __restrict__ log_A_real,
    const float* __restrict__ A_imag,
    float* __restrict__ out)
{
    __shared__ float s_lr[NH], s_li[NH], s_re2[NH], s_hi[NH], s_lo[NH];

    const int h = blockIdx.y;
    const int l = blockIdx.x * LT + threadIdx.x;

    // ---- per-block setup: threads 0..31 compute per-n constants ----
    if (threadIdx.x < NH) {
        const int n = threadIdx.x;
        const int hn = h * NH + n;

        const float dt = expf(log_dt[h]);
        const float Ar = -expf(log_A_real[hn]);
        const float Ai = A_imag[hn];
        const float dtAr = Ar * dt;
        const float dtAi = Ai * dt;

        // exp(dtA) - 1  (accurate setup-time math)
        const float er = expf(dtAr);
        float sn, cs;
        sincosf(dtAi, &sn, &cs);
        const float Er = er * cs - 1.0f;
        const float Ei = er * sn;

        // lhs = C * (exp(dtA)-1) / A, folded ×2
        const float cr = C_ri[2 * hn + 0];
        const float ci = C_ri[2 * hn + 1];
        const float nr = cr * Er - ci * Ei;
        const float ni = cr * Ei + ci * Er;
        const float inv = 1.0f / (Ar * Ar + Ai * Ai);
        s_lr[n] = 2.0f * (nr * Ar + ni * Ai) * inv;
        s_li[n] = 2.0f * (ni * Ar - nr * Ai) * inv;

        // decay exponent in log2 units: e^{dtAr·l} = 2^{re2·l}
        s_re2[n] = dtAr * 1.4426950408889634f;

        // phase step in revolutions per l, exact hi/lo split:
        //   hi = multiple of 2^-12 in [0,1]  ->  hi*l exact in fp32 (product < 2^24)
        //   lo = residual, |lo| <= 2^-13     ->  |lo*l| <= 0.5 rev
        const double sd = (double)dtAi * 0.15915494309189535; // /(2*pi)
        const double fd = sd - floor(sd);
        const float hi = (float)(floor(fd * 4096.0 + 0.5) * (1.0 / 4096.0));
        s_hi[n] = hi;
        s_lo[n] = (float)(fd - (double)hi);
    }
    __syncthreads();

    // ---- main: each thread computes one output element ----
    const float lf = (float)l;
    float acc = 0.0f;

#pragma unroll
    for (int n = 0; n < NH; ++n) {
        // phase (revolutions), exactly reduced
        const float x  = s_hi[n] * lf;          // exact
        const float fr = x - floorf(x);         // exact fract
        float rev = fmaf(s_lo[n], lf, fr);      // in (-0.5, 1.5)
        rev = rev - floorf(rev);                // [0, 1)
        const float ang = rev * 6.283185307179586f;

        const float sn = __sinf(ang);
        const float cs = __cosf(ang);
        const float e  = exp2f(s_re2[n] * lf);  // decay, underflow->0 ok

        // += e * (lr*cos - li*sin)
        acc = fmaf(e, fmaf(s_lr[n], cs, -s_li[n] * sn), acc);
    }

    out[h * LLEN + l] = acc;
}

extern "C" void kernel_launch(void* const* d_in, const int* in_sizes, int n_in,
                              void* d_out, int out_size, void* d_ws, size_t ws_size,
                              hipStream_t stream) {
    const float* C_ri       = (const float*)d_in[0];
    const float* log_dt     = (const float*)d_in[1];
    const float* log_A_real = (const float*)d_in[2];
    const float* A_imag     = (const float*)d_in[3];
    float* out = (float*)d_out;

    dim3 grid(LLEN / LT, HDIM);
    dim3 block(LT);
    s4d_kernel<<<grid, block, 0, stream>>>(C_ri, log_dt, log_A_real, A_imag, out);
}

// Round 2
// 24.314 us; speedup vs baseline: 3.3693x; 3.3693x over previous
//
#include <hip/hip_runtime.h>
#include <math.h>

#define HDIM 1024
#define NH 32
#define NPAIR (NH / 2)
#define LLEN 4096
#define NT 256
#define TSTEPS (LLEN / NT)   // 16 l-values per thread, stride NT

typedef float v2f __attribute__((ext_vector_type(2)));

__global__ __launch_bounds__(NT) void s4d_kernel(
    const float* __restrict__ C_ri,
    const float* __restrict__ log_dt,
    const float* __restrict__ log_A_real,
    const float* __restrict__ A_imag,
    float* __restrict__ out)
{
    __shared__ v2f s_lr[NPAIR], s_li[NPAIR], s_re2[NPAIR], s_hi[NPAIR],
                   s_lo[NPAIR], s_wr[NPAIR], s_wi[NPAIR];

    const int h = blockIdx.x;
    const int tid = threadIdx.x;

    // ---- setup: threads 0..31, one n each ----
    if (tid < NH) {
        const int n = tid;
        const int hn = h * NH + n;

        const float dt = expf(log_dt[h]);
        const float Ar = -expf(log_A_real[hn]);
        const float Ai = A_imag[hn];
        const float dtAr = Ar * dt;
        const float dtAi = Ai * dt;

        // lhs = 2 * C * (exp(dtA)-1) / A
        const float er = expf(dtAr);
        float sn, cs;
        sincosf(dtAi, &sn, &cs);
        const float Er = er * cs - 1.0f;
        const float Ei = er * sn;
        const float cr = C_ri[2 * hn + 0];
        const float ci = C_ri[2 * hn + 1];
        const float nr = cr * Er - ci * Ei;
        const float ni = cr * Ei + ci * Er;
        const float inv = 1.0f / (Ar * Ar + Ai * Ai);
        ((float*)s_lr)[n] = 2.0f * (nr * Ar + ni * Ai) * inv;
        ((float*)s_li)[n] = 2.0f * (ni * Ar - nr * Ai) * inv;

        // decay exponent (log2 units)
        const float re2 = dtAr * 1.4426950408889634f;
        ((float*)s_re2)[n] = re2;

        // phase step (revolutions/l), exact hi/lo split for init at l=tid<256
        const double sd = (double)dtAi * 0.15915494309189535;
        const double fd = sd - floor(sd);
        const float hi = (float)(floor(fd * 4096.0 + 0.5) * (1.0 / 4096.0));
        ((float*)s_hi)[n] = hi;
        ((float*)s_lo)[n] = (float)(fd - (double)hi);

        // w256 = exp(dtA * 256): recurrence step multiplier
        double r256 = fd * 256.0;
        r256 -= floor(r256);
        const float e256 = exp2f(re2 * 256.0f);
        float sw, cw;
        sincosf((float)r256 * 6.283185307179586f, &sw, &cw);
        ((float*)s_wr)[n] = e256 * cw;
        ((float*)s_wi)[n] = e256 * sw;
    }
    __syncthreads();

    v2f acc[TSTEPS];
#pragma unroll
    for (int t = 0; t < TSTEPS; ++t) acc[t] = (v2f){0.0f, 0.0f};

    const float lf = (float)tid;

    for (int j = 0; j < NPAIR; ++j) {
        const v2f lr = s_lr[j], li = s_li[j];
        const v2f wr = s_wr[j], wi = s_wi[j];
        const v2f hi = s_hi[j], lo = s_lo[j], re2 = s_re2[j];

        // init z = exp(dtA * tid) for both lanes of the pair
        v2f zr, zi;
#pragma unroll
        for (int c = 0; c < 2; ++c) {
            const float x = hi[c] * lf;            // exact (12-bit hi × int<256)
            const float fr = x - floorf(x);
            float rev = fmaf(lo[c], lf, fr);
            rev = rev - floorf(rev);               // [0,1) revolutions
            const float e = exp2f(re2[c] * lf);
            zr[c] = e * __builtin_amdgcn_cosf(rev); // HW takes revolutions
            zi[c] = e * __builtin_amdgcn_sinf(rev);
        }

        // 16 recurrence steps: acc += Re(lhs * z); z *= w256
#pragma unroll
        for (int t = 0; t < TSTEPS; ++t) {
            acc[t] += lr * zr;
            acc[t] -= li * zi;
            const v2f tr = zr * wr - zi * wi;
            const v2f ti = zr * wi + zi * wr;
            zr = tr;
            zi = ti;
        }
    }

#pragma unroll
    for (int t = 0; t < TSTEPS; ++t)
        out[h * LLEN + t * NT + tid] = acc[t].x + acc[t].y;
}

extern "C" void kernel_launch(void* const* d_in, const int* in_sizes, int n_in,
                              void* d_out, int out_size, void* d_ws, size_t ws_size,
                              hipStream_t stream) {
    const float* C_ri       = (const float*)d_in[0];
    const float* log_dt     = (const float*)d_in[1];
    const float* log_A_real = (const float*)d_in[2];
    const float* A_imag     = (const float*)d_in[3];
    float* out = (float*)d_out;

    s4d_kernel<<<dim3(HDIM), dim3(NT), 0, stream>>>(C_ri, log_dt, log_A_real, A_imag, out);
}

// Round 3
// 19.357 us; speedup vs baseline: 4.2322x; 1.2561x over previous
//
#include <hip/hip_runtime.h>
#include <math.h>

#define HDIM 1024
#define NH 32
#define NPAIR (NH / 2)
#define LLEN 4096
#define NT 256
#define TSTEPS (LLEN / NT)   // 16 l-values per thread, stride NT

typedef float v2f __attribute__((ext_vector_type(2)));

__global__ __launch_bounds__(NT) void s4d_kernel(
    const float* __restrict__ C_ri,
    const float* __restrict__ log_dt,
    const float* __restrict__ log_A_real,
    const float* __restrict__ A_imag,
    float* __restrict__ out)
{
    __shared__ v2f s_lr[NPAIR], s_li[NPAIR], s_hi[NPAIR], s_lo[NPAIR],
                   s_re2[NPAIR], s_wr[NPAIR], s_wi[NPAIR], s_b[NPAIR];

    const int h = blockIdx.x;
    const int tid = threadIdx.x;

    // ---- setup: threads 0..31, one n each ----
    if (tid < NH) {
        const int n = tid;
        const int hn = h * NH + n;

        const float dt = expf(log_dt[h]);
        const float Ar = -expf(log_A_real[hn]);
        const float Ai = A_imag[hn];
        const float dtAr = Ar * dt;
        const float dtAi = Ai * dt;

        // lhs = 2 * C * (exp(dtA)-1) / A
        const float er = expf(dtAr);
        float sn, cs;
        sincosf(dtAi, &sn, &cs);
        const float Er = er * cs - 1.0f;
        const float Ei = er * sn;
        const float cr = C_ri[2 * hn + 0];
        const float ci = C_ri[2 * hn + 1];
        const float nr = cr * Er - ci * Ei;
        const float ni = cr * Ei + ci * Er;
        const float inv = 1.0f / (Ar * Ar + Ai * Ai);
        ((float*)s_lr)[n] = 2.0f * (nr * Ar + ni * Ai) * inv;
        ((float*)s_li)[n] = 2.0f * (ni * Ar - nr * Ai) * inv;

        // decay exponent (log2 units)
        const float re2 = dtAr * 1.4426950408889634f;
        ((float*)s_re2)[n] = re2;

        // phase step (revolutions/l), exact hi/lo split (init uses l=tid<256)
        const double sd = (double)dtAi * 0.15915494309189535;
        const double fd = sd - floor(sd);
        const float hi = (float)(floor(fd * 4096.0 + 0.5) * (1.0 / 4096.0));
        ((float*)s_hi)[n] = hi;
        ((float*)s_lo)[n] = (float)(fd - (double)hi);

        // w = exp(dtA * 256): recurrence multiplier
        double r256 = fd * 256.0;
        r256 -= floor(r256);
        const float e256 = exp2f(re2 * 256.0f);
        float sw, cw;
        sincosf((float)r256 * 6.283185307179586f, &sw, &cw);
        const float wr = e256 * cw;
        const float wi = e256 * sw;
        ((float*)s_wr)[n] = wr;
        ((float*)s_wi)[n] = wi;
        // b = -|w|^2  (2nd-order real recurrence coefficient)
        ((float*)s_b)[n] = -(e256 * e256);
    }
    __syncthreads();

    v2f acc[TSTEPS];
#pragma unroll
    for (int t = 0; t < TSTEPS; ++t) acc[t] = (v2f){0.0f, 0.0f};

    const float lf = (float)tid;

#pragma unroll 4
    for (int j = 0; j < NPAIR; ++j) {
        const v2f lr = s_lr[j], li = s_li[j];
        const v2f hi = s_hi[j], lo = s_lo[j], re2 = s_re2[j];
        const v2f wr = s_wr[j], wi = s_wi[j], b = s_b[j];

        // z0 = exp(dtA * tid)  (exact phase reduction; HW sin/cos in revs)
        v2f zr, zi;
#pragma unroll
        for (int c = 0; c < 2; ++c) {
            const float x = hi[c] * lf;            // exact (12-bit hi × int<256)
            const float fr = x - floorf(x);
            float rev = fmaf(lo[c], lf, fr);
            rev = rev - floorf(rev);               // [0,1) revolutions
            const float e = exp2f(re2[c] * lf);
            zr[c] = e * __builtin_amdgcn_cosf(rev);
            zi[c] = e * __builtin_amdgcn_sinf(rev);
        }

        // y0 = lhs*z0 ; y1 = y0*w ; then real 2nd-order recurrence:
        //   yr_{t+2} = 2*Re(w)*yr_{t+1} - |w|^2 * yr_t
        const v2f yr0 = lr * zr - li * zi;
        const v2f yi0 = lr * zi + li * zr;
        const v2f yr1 = wr * yr0 - wi * yi0;
        const v2f a = wr + wr;

        acc[0] += yr0;
        acc[1] += yr1;
        v2f y0 = yr0, y1 = yr1;
#pragma unroll
        for (int t = 2; t < TSTEPS; ++t) {
            const v2f y2 = a * y1 + b * y0;        // fma + off-path mul
            acc[t] += y2;
            y0 = y1;
            y1 = y2;
        }
    }

#pragma unroll
    for (int t = 0; t < TSTEPS; ++t)
        out[h * LLEN + t * NT + tid] = acc[t].x + acc[t].y;
}

extern "C" void kernel_launch(void* const* d_in, const int* in_sizes, int n_in,
                              void* d_out, int out_size, void* d_ws, size_t ws_size,
                              hipStream_t stream) {
    const float* C_ri       = (const float*)d_in[0];
    const float* log_dt     = (const float*)d_in[1];
    const float* log_A_real = (const float*)d_in[2];
    const float* A_imag     = (const float*)d_in[3];
    float* out = (float*)d_out;

    s4d_kernel<<<dim3(HDIM), dim3(NT), 0, stream>>>(C_ri, log_dt, log_A_real, A_imag, out);
}

// Round 4
// 16.591 us; speedup vs baseline: 4.9378x; 1.1667x over previous
//
#include <hip/hip_runtime.h>
#include <math.h>

#define HDIM 1024
#define NH 32
#define NPAIR 16
#define LLEN 4096
#define NT 256
#define TSTEPS 16
#define GP 8   // pairs per register group

typedef float v2f __attribute__((ext_vector_type(2)));

__global__ __launch_bounds__(NT) void s4d_kernel(
    const float* __restrict__ C_ri,
    const float* __restrict__ log_dt,
    const float* __restrict__ log_A_real,
    const float* __restrict__ A_imag,
    float* __restrict__ out)
{
    // per-n scalars for table build
    __shared__ float s_hi[NH], s_lo[NH], s_re2[NH];
    // per-pair coefficients (component c = n = 2j+c), v2f-aligned
    __shared__ v2f s_lr[NPAIR], s_li[NPAIR], s_wr[NPAIR], s_wi[NPAIR],
                   s_a[NPAIR], s_b[NPAIR];
    // z0 tables: T[0]=P (step 16), T[1]=Q (step 1); [pair][idx][0=re,1=im]
    __shared__ v2f s_T[2][NPAIR][16][2];

    const int h = blockIdx.x;
    const int tid = threadIdx.x;

    // ---- setup: threads 0..31, one n each ----
    if (tid < NH) {
        const int n = tid;
        const int hn = h * NH + n;

        const float dt = expf(log_dt[h]);
        const float Ar = -expf(log_A_real[hn]);
        const float Ai = A_imag[hn];
        const float dtAr = Ar * dt;
        const float dtAi = Ai * dt;

        // lhs = 2 * C * (exp(dtA)-1) / A
        const float er = expf(dtAr);
        float sn, cs;
        sincosf(dtAi, &sn, &cs);
        const float Er = er * cs - 1.0f;
        const float Ei = er * sn;
        const float cr = C_ri[2 * hn + 0];
        const float ci = C_ri[2 * hn + 1];
        const float nr = cr * Er - ci * Ei;
        const float ni = cr * Ei + ci * Er;
        const float inv = 1.0f / (Ar * Ar + Ai * Ai);
        ((float*)s_lr)[n] = 2.0f * (nr * Ar + ni * Ai) * inv;
        ((float*)s_li)[n] = 2.0f * (ni * Ar - nr * Ai) * inv;

        // decay exponent (log2 units), exact hi/lo phase split (rev/step)
        const float re2 = dtAr * 1.4426950408889634f;
        s_re2[n] = re2;
        const double sd = (double)dtAi * 0.15915494309189535;
        const double fd = sd - floor(sd);
        const float hi = (float)(floor(fd * 4096.0 + 0.5) * (1.0 / 4096.0));
        s_hi[n] = hi;
        s_lo[n] = (float)(fd - (double)hi);

        // w = exp(dtA * 256): recurrence multiplier; a = 2Re(w), b = -|w|^2
        double r256 = fd * 256.0;
        r256 -= floor(r256);
        const float e256 = exp2f(re2 * 256.0f);
        float sw, cw;
        sincosf((float)r256 * 6.283185307179586f, &sw, &cw);
        const float wr = e256 * cw;
        const float wi = e256 * sw;
        ((float*)s_wr)[n] = wr;
        ((float*)s_wi)[n] = wi;
        ((float*)s_a)[n] = wr + wr;
        ((float*)s_b)[n] = -(e256 * e256);
    }
    __syncthreads();

    // ---- z0 tables: 1024 entries, 4 per thread ----
    // entry e: tbl = e>>9 (0:P step16, 1:Q step1), pair j = (e>>5)&15,
    //          idx = (e>>1)&15, component c = e&1, n = 2j+c, m = idx*(16 or 1)
#pragma unroll
    for (int k = 0; k < 4; ++k) {
        const int e = tid + NT * k;
        const int tbl = e >> 9;
        const int j = (e >> 5) & 15;
        const int idx = (e >> 1) & 15;
        const int c = e & 1;
        const int n = 2 * j + c;
        const float m = (float)(tbl ? idx : idx * 16);
        const float x = s_hi[n] * m;           // exact: 12-bit hi × int<=240
        const float fr = x - floorf(x);
        float rev = fmaf(s_lo[n], m, fr);
        rev -= floorf(rev);                    // [0,1) revolutions
        const float ev = exp2f(s_re2[n] * m);
        float* dst = (float*)&s_T[tbl][j][idx][0] + c;
        dst[0] = ev * __builtin_amdgcn_cosf(rev);  // re at [idx][0]
        dst[2] = ev * __builtin_amdgcn_sinf(rev);  // im at [idx][1]
    }
    __syncthreads();

    // ---- main ----
    const int hi_idx = tid >> 4;
    const int lo_idx = tid & 15;

    v2f acc[TSTEPS];
#pragma unroll
    for (int t = 0; t < TSTEPS; ++t) acc[t] = (v2f){0.0f, 0.0f};

    for (int g = 0; g < 2; ++g) {
        v2f Y0[GP], Y1[GP], A[GP], B[GP];

        // phase 1: per-pair init, everything into registers
#pragma unroll
        for (int jj = 0; jj < GP; ++jj) {
            const int j = g * GP + jj;
            const v2f Pr = s_T[0][j][hi_idx][0];
            const v2f Pi = s_T[0][j][hi_idx][1];
            const v2f Qr = s_T[1][j][lo_idx][0];
            const v2f Qi = s_T[1][j][lo_idx][1];
            const v2f zr = Pr * Qr - Pi * Qi;  // z0 = exp(dtA * tid)
            const v2f zi = Pr * Qi + Pi * Qr;
            const v2f lr = s_lr[j], li = s_li[j];
            const v2f wr = s_wr[j], wi = s_wi[j];
            const v2f y0 = lr * zr - li * zi;  // Re(lhs*z0)
            const v2f yi0 = lr * zi + li * zr;
            Y0[jj] = y0;
            Y1[jj] = wr * y0 - wi * yi0;       // Re(lhs*z0*w)
            A[jj] = s_a[j];
            B[jj] = s_b[j];
        }

        // phase 2: register-resident 2nd-order recurrence
#pragma unroll
        for (int jj = 0; jj < GP; ++jj) {
            acc[0] += Y0[jj];
            acc[1] += Y1[jj];
        }
#pragma unroll
        for (int t = 2; t < TSTEPS; ++t) {
#pragma unroll
            for (int jj = 0; jj < GP; ++jj) {
                const v2f y2 = A[jj] * Y1[jj] + B[jj] * Y0[jj];
                acc[t] += y2;
                Y0[jj] = Y1[jj];
                Y1[jj] = y2;
            }
        }
    }

    const int base = h * LLEN + tid;
#pragma unroll
    for (int t = 0; t < TSTEPS; ++t)
        out[base + t * NT] = acc[t].x + acc[t].y;
}

extern "C" void kernel_launch(void* const* d_in, const int* in_sizes, int n_in,
                              void* d_out, int out_size, void* d_ws, size_t ws_size,
                              hipStream_t stream) {
    const float* C_ri       = (const float*)d_in[0];
    const float* log_dt     = (const float*)d_in[1];
    const float* log_A_real = (const float*)d_in[2];
    const float* A_imag     = (const float*)d_in[3];
    float* out = (float*)d_out;

    s4d_kernel<<<dim3(HDIM), dim3(NT), 0, stream>>>(C_ri, log_dt, log_A_real, A_imag, out);
}

// Round 5
// 16.532 us; speedup vs baseline: 4.9552x; 1.0035x over previous
//
#include <hip/hip_runtime.h>
#include <math.h>

#define HDIM 1024
#define NH 32
#define NPAIR 16
#define LLEN 4096
#define NT 256
#define TSTEPS 16
#define GP 4
#define NGROUP (NPAIR / GP)

typedef float v2f __attribute__((ext_vector_type(2)));

__global__ __launch_bounds__(NT, 4) void s4d_kernel(
    const float* __restrict__ C_ri,
    const float* __restrict__ log_dt,
    const float* __restrict__ log_A_real,
    const float* __restrict__ A_imag,
    float* __restrict__ out)
{
    __shared__ float s_hi[NH], s_lo[NH], s_re2[NH];
    // per-pair coeffs: [0]={lr0,lr1,li0,li1} [1]={wr0,wr1,wi0,wi1} [2]={a0,a1,b0,b1}
    __shared__ float4 s_cf[NPAIR][3];
    // z0 tables: [0]=P (step 16), [1]=Q (step 1); entry = {re0,re1,im0,im1}
    __shared__ float4 s_T[2][NPAIR][16];

    const int h = blockIdx.x;
    const int tid = threadIdx.x;

    // ---- setup: threads 0..31, one n each ----
    if (tid < NH) {
        const int n = tid;
        const int hn = h * NH + n;

        const float dt = expf(log_dt[h]);
        const float Ar = -expf(log_A_real[hn]);
        const float Ai = A_imag[hn];
        const float dtAr = Ar * dt;
        const float dtAi = Ai * dt;

        // lhs = 2 * C * (exp(dtA)-1) / A
        const float er = expf(dtAr);
        float sn, cs;
        sincosf(dtAi, &sn, &cs);
        const float Er = er * cs - 1.0f;
        const float Ei = er * sn;
        const float cr = C_ri[2 * hn + 0];
        const float ci = C_ri[2 * hn + 1];
        const float nr = cr * Er - ci * Ei;
        const float ni = cr * Ei + ci * Er;
        const float inv = 1.0f / (Ar * Ar + Ai * Ai);
        const float lr = 2.0f * (nr * Ar + ni * Ai) * inv;
        const float li = 2.0f * (ni * Ar - nr * Ai) * inv;

        // decay exponent (log2 units), exact hi/lo phase split (rev/step)
        const float re2 = dtAr * 1.4426950408889634f;
        s_re2[n] = re2;
        const double sd = (double)dtAi * 0.15915494309189535;
        const double fd = sd - floor(sd);
        const float hi = (float)(floor(fd * 4096.0 + 0.5) * (1.0 / 4096.0));
        s_hi[n] = hi;
        s_lo[n] = (float)(fd - (double)hi);

        // w = exp(dtA*256); a = 2Re(w), b = -|w|^2
        double r256 = fd * 256.0;
        r256 -= floor(r256);
        const float e256 = exp2f(re2 * 256.0f);
        float sw, cw;
        sincosf((float)r256 * 6.283185307179586f, &sw, &cw);
        const float wr = e256 * cw;
        const float wi = e256 * sw;

        const int j = n >> 1;
        const int c = n & 1;
        float* f0 = (float*)&s_cf[j][0]; f0[c] = lr; f0[2 + c] = li;
        float* f1 = (float*)&s_cf[j][1]; f1[c] = wr; f1[2 + c] = wi;
        float* f2 = (float*)&s_cf[j][2]; f2[c] = wr + wr; f2[2 + c] = -(e256 * e256);
    }
    __syncthreads();

    // ---- z0 tables: 1024 complex entries, 4 per thread ----
#pragma unroll
    for (int k = 0; k < 4; ++k) {
        const int e = tid + NT * k;
        const int tbl = e >> 9;
        const int j = (e >> 5) & 15;
        const int idx = (e >> 1) & 15;
        const int c = e & 1;
        const int n = 2 * j + c;
        const float m = (float)(tbl ? idx : idx * 16);
        const float x = s_hi[n] * m;          // exact: 12-bit hi × int<=240
        const float fr = x - floorf(x);
        float rev = fmaf(s_lo[n], m, fr);
        rev -= floorf(rev);                   // [0,1) revolutions
        const float ev = exp2f(s_re2[n] * m);
        float* dst = (float*)&s_T[tbl][j][idx];
        dst[c]     = ev * __builtin_amdgcn_cosf(rev);
        dst[2 + c] = ev * __builtin_amdgcn_sinf(rev);
    }
    __syncthreads();

    // ---- main ----
    const int hi_idx = tid >> 4;
    const int lo_idx = tid & 15;

    v2f acc[TSTEPS];
#pragma unroll
    for (int t = 0; t < TSTEPS; ++t) acc[t] = (v2f){0.0f, 0.0f};

#pragma unroll
    for (int g = 0; g < NGROUP; ++g) {
        v2f Y0[GP], Y1[GP], A[GP], B[GP];

#pragma unroll
        for (int jj = 0; jj < GP; ++jj) {
            const int j = g * GP + jj;
            const float4 P  = s_T[0][j][hi_idx];
            const float4 Q  = s_T[1][j][lo_idx];
            const float4 c0 = s_cf[j][0];
            const float4 c1 = s_cf[j][1];
            const float4 c2 = s_cf[j][2];
            const v2f Pr = (v2f){P.x, P.y},  Pi = (v2f){P.z, P.w};
            const v2f Qr = (v2f){Q.x, Q.y},  Qi = (v2f){Q.z, Q.w};
            const v2f lr = (v2f){c0.x, c0.y}, li = (v2f){c0.z, c0.w};
            const v2f wr = (v2f){c1.x, c1.y}, wi = (v2f){c1.z, c1.w};
            A[jj] = (v2f){c2.x, c2.y};
            B[jj] = (v2f){c2.z, c2.w};

            const v2f zr = Pr * Qr - Pi * Qi;   // z0 = exp(dtA*tid)
            const v2f zi = Pr * Qi + Pi * Qr;
            const v2f y0  = lr * zr - li * zi;  // Re(lhs*z0)
            const v2f yi0 = lr * zi + li * zr;
            Y0[jj] = y0;
            Y1[jj] = wr * y0 - wi * yi0;        // Re(lhs*z0*w)
            acc[0] += y0;
            acc[1] += Y1[jj];
        }

#pragma unroll
        for (int t = 2; t < TSTEPS; ++t) {
#pragma unroll
            for (int jj = 0; jj < GP; ++jj) {
                const v2f y2 = A[jj] * Y1[jj] + B[jj] * Y0[jj];
                acc[t] += y2;
                Y0[jj] = Y1[jj];
                Y1[jj] = y2;
            }
        }
    }

    const int base = h * LLEN + tid;
#pragma unroll
    for (int t = 0; t < TSTEPS; ++t)
        out[base + t * NT] = acc[t].x + acc[t].y;
}

extern "C" void kernel_launch(void* const* d_in, const int* in_sizes, int n_in,
                              void* d_out, int out_size, void* d_ws, size_t ws_size,
                              hipStream_t stream) {
    const float* C_ri       = (const float*)d_in[0];
    const float* log_dt     = (const float*)d_in[1];
    const float* log_A_real = (const float*)d_in[2];
    const float* A_imag     = (const float*)d_in[3];
    float* out = (float*)d_out;

    s4d_kernel<<<dim3(HDIM), dim3(NT), 0, stream>>>(C_ri, log_dt, log_A_real, A_imag, out);
}

// Round 6
// 14.335 us; speedup vs baseline: 5.7148x; 1.1533x over previous
//
#include <hip/hip_runtime.h>
#include <math.h>

#define HDIM 1024
#define NH 32
#define LLEN 4096
#define NT 256
#define QN 64
#define RN 64
#define LDK 72   // padded k-stride in bf16 elems (144 B = 36 dwords, %32=4)

typedef __attribute__((ext_vector_type(8))) short bf16x8;
typedef __attribute__((ext_vector_type(4))) float f32x4;

__device__ __forceinline__ unsigned short f2bf(float x) {
    unsigned int u = __builtin_bit_cast(unsigned int, x);
    unsigned int r = (u + 0x7FFFu + ((u >> 16) & 1u)) >> 16;
    return (unsigned short)r;
}
__device__ __forceinline__ float bf2f(unsigned short h) {
    unsigned int u = ((unsigned int)h) << 16;
    return __builtin_bit_cast(float, u);
}

__global__ __launch_bounds__(NT, 4) void s4d_kernel(
    const float* __restrict__ C_ri,
    const float* __restrict__ log_dt,
    const float* __restrict__ log_A_real,
    const float* __restrict__ A_imag,
    float* __restrict__ out)
{
    __shared__ float s_hi[NH], s_lo[NH], s_re2[NH], s_lr[NH], s_li[NH];
    __shared__ unsigned short sAh[QN][LDK], sAl[QN][LDK];
    __shared__ unsigned short sBh[RN][LDK], sBl[RN][LDK];

    const int h = blockIdx.x;
    const int tid = threadIdx.x;

    // ---- per-mode setup (threads 0..31) ----
    if (tid < NH) {
        const int n = tid;
        const int hn = h * NH + n;

        const float dt = expf(log_dt[h]);
        const float Ar = -expf(log_A_real[hn]);
        const float Ai = A_imag[hn];
        const float dtAr = Ar * dt;
        const float dtAi = Ai * dt;

        // lhs = 2 * C * (exp(dtA)-1) / A  (the x2 folded into A-matrix build)
        const float er = expf(dtAr);
        float sn, cs;
        sincosf(dtAi, &sn, &cs);
        const float Er = er * cs - 1.0f;
        const float Ei = er * sn;
        const float cr = C_ri[2 * hn + 0];
        const float ci = C_ri[2 * hn + 1];
        const float nr = cr * Er - ci * Ei;
        const float ni = cr * Ei + ci * Er;
        const float inv = 1.0f / (Ar * Ar + Ai * Ai);
        s_lr[n] = (nr * Ar + ni * Ai) * inv;
        s_li[n] = (ni * Ar - nr * Ai) * inv;

        // decay exponent (log2 units); exact hi/lo split of phase step (rev/l)
        const float re2 = dtAr * 1.4426950408889634f;
        s_re2[n] = re2;
        const double sd = (double)dtAi * 0.15915494309189535;
        const double fd = sd - floor(sd);
        const float hi = (float)(floor(fd * 4096.0 + 0.5) * (1.0 / 4096.0));
        s_hi[n] = hi;
        s_lo[n] = (float)(fd - (double)hi);
    }
    __syncthreads();

    // ---- build A (q x k) and BT (r x k) tables, bf16 hi/lo split ----
    // 4096 complex entries, 16 per thread. e>>11: 0=A-table, 1=B-table.
#pragma unroll
    for (int k = 0; k < 16; ++k) {
        const int e = tid + NT * k;
        const int isB = e >> 11;
        const int idx = e & 2047;
        const int n = idx & 31;
        const int row = idx >> 5;                   // q or r in [0,64)
        const float m = (float)(isB ? row : row * 64);

        const float x = s_hi[n] * m;                // exact: hi=j/4096, j*m<2^24
        const float fr = x - floorf(x);
        float rev = fmaf(s_lo[n], m, fr);
        rev -= floorf(rev);                         // [0,1) revolutions
        const float ev = exp2f(s_re2[n] * m);       // underflow->0 matches ref
        const float zr = ev * __builtin_amdgcn_cosf(rev);
        const float zi = ev * __builtin_amdgcn_sinf(rev);

        float ar, ai;
        if (isB) {
            ar = zr; ai = zi;                       // BT[r][2n]=Re, [2n+1]=Im
        } else {
            const float lr = s_lr[n], li = s_li[n];
            ar =  2.0f * (lr * zr - li * zi);       // 2*Re(lhs*z^{64q})
            ai = -2.0f * (lr * zi + li * zr);       // -2*Im(lhs*z^{64q})
        }

        const unsigned short hr = f2bf(ar);
        const unsigned short hj = f2bf(ai);
        const unsigned short lr2 = f2bf(ar - bf2f(hr));
        const unsigned short lj2 = f2bf(ai - bf2f(hj));
        const unsigned int hpack = (unsigned int)hr | ((unsigned int)hj << 16);
        const unsigned int lpack = (unsigned int)lr2 | ((unsigned int)lj2 << 16);
        if (isB) {
            *(unsigned int*)&sBh[row][2 * n] = hpack;
            *(unsigned int*)&sBl[row][2 * n] = lpack;
        } else {
            *(unsigned int*)&sAh[row][2 * n] = hpack;
            *(unsigned int*)&sAl[row][2 * n] = lpack;
        }
    }
    __syncthreads();

    // ---- MFMA: wave w owns q in [16w, 16w+16); C = Ah*Bh + Ah*Bl + Al*Bh ----
    const int wv = tid >> 6;
    const int lane = tid & 63;
    const int li16 = lane & 15;
    const int lg = lane >> 4;

    f32x4 acc[4];
#pragma unroll
    for (int tc = 0; tc < 4; ++tc) acc[tc] = (f32x4){0.f, 0.f, 0.f, 0.f};

    // K-steps: s=0,1: Ah*Bh (kb 0,32); s=2,3: Ah*Bl; s=4,5: Al*Bh
#pragma unroll
    for (int s = 0; s < 6; ++s) {
        const unsigned short (*Am)[LDK] = (s >= 4) ? sAl : sAh;
        const unsigned short (*Bm)[LDK] = (s == 2 || s == 3) ? sBl : sBh;
        const int kb = (s & 1) * 32;
        const int ko = kb + 8 * lg;                 // k-offset, 16B aligned

        const bf16x8 af = *(const bf16x8*)&Am[16 * wv + li16][ko];
#pragma unroll
        for (int tc = 0; tc < 4; ++tc) {
            const bf16x8 bfr = *(const bf16x8*)&Bm[16 * tc + li16][ko];
            acc[tc] = __builtin_amdgcn_mfma_f32_16x16x32_bf16(af, bfr, acc[tc], 0, 0, 0);
        }
    }

    // ---- C write: D col=lane&15, row=(lane>>4)*4+reg ; l = 64q + r ----
    const int obase = h * LLEN;
#pragma unroll
    for (int tc = 0; tc < 4; ++tc) {
        const int r = 16 * tc + li16;
#pragma unroll
        for (int reg = 0; reg < 4; ++reg) {
            const int q = 16 * wv + 4 * lg + reg;
            out[obase + 64 * q + r] = acc[tc][reg];
        }
    }
}

extern "C" void kernel_launch(void* const* d_in, const int* in_sizes, int n_in,
                              void* d_out, int out_size, void* d_ws, size_t ws_size,
                              hipStream_t stream) {
    const float* C_ri       = (const float*)d_in[0];
    const float* log_dt     = (const float*)d_in[1];
    const float* log_A_real = (const float*)d_in[2];
    const float* A_imag     = (const float*)d_in[3];
    float* out = (float*)d_out;

    s4d_kernel<<<dim3(HDIM), dim3(NT), 0, stream>>>(C_ri, log_dt, log_A_real, A_imag, out);
}

// Round 7
// 13.283 us; speedup vs baseline: 6.1672x; 1.0792x over previous
//
#include <hip/hip_runtime.h>
#include <math.h>

#define HDIM 1024
#define NH 32
#define LLEN 4096
#define NT 256
#define LDK 72   // padded k-stride in bf16 elems (144 B = 36 dwords, %32=4 -> <=2-way, free)

typedef __attribute__((ext_vector_type(8))) short bf16x8;
typedef __attribute__((ext_vector_type(4))) float f32x4;

__device__ __forceinline__ unsigned int fbits(float x) {
    return __builtin_bit_cast(unsigned int, x);
}
__device__ __forceinline__ float bitsf(unsigned int u) {
    return __builtin_bit_cast(float, u);
}

__global__ __launch_bounds__(NT, 4) void s4d_kernel(
    const float* __restrict__ C_ri,
    const float* __restrict__ log_dt,
    const float* __restrict__ log_A_real,
    const float* __restrict__ A_imag,
    float* __restrict__ out)
{
    // A-table: rows r in [0,64), entries z_n^r          (plain)
    // B-table: rows q in [0,64), entries lhs_n * z_n^{64q} (x2 / -x2 folded)
    __shared__ unsigned short sAh[64][LDK], sAl[64][LDK];
    __shared__ unsigned short sBh[64][LDK], sBl[64][LDK];

    const int h = blockIdx.x;
    const int tid = threadIdx.x;
    const int n = tid & 31;         // this thread's mode (all its entries use it)
    const int hn = h * NH + n;
    const int r0 = tid >> 5;        // 0..7: row residue

    // ---- per-thread setup (redundant x8 across threads; all in registers) ----
    const float dt = expf(log_dt[h]);
    const float Ar = -expf(log_A_real[hn]);
    const float Ai = A_imag[hn];
    const float dtAr = Ar * dt;
    const float dtAi = Ai * dt;

    const float er = expf(dtAr);
    float sn, cs;
    sincosf(dtAi, &sn, &cs);
    const float Er = er * cs - 1.0f;
    const float Ei = er * sn;
    const float cr = C_ri[2 * hn + 0];
    const float ci = C_ri[2 * hn + 1];
    const float nr = cr * Er - ci * Ei;
    const float ni = cr * Ei + ci * Er;
    const float inv = 1.0f / (Ar * Ar + Ai * Ai);
    const float lr = (nr * Ar + ni * Ai) * inv;   // lhs (x2 applied at B build)
    const float li = (ni * Ar - nr * Ai) * inv;

    const float re2 = dtAr * 1.4426950408889634f;  // decay in log2/l
    const double sd = (double)dtAi * 0.15915494309189535;
    const double fdd = sd - floor(sd);
    const float phi = (float)(floor(fdd * 4096.0 + 0.5) * (1.0 / 4096.0));
    const float plo = (float)(fdd - (double)phi);  // exact hi/lo split (rev/l)

    // ---- A-table: z^r, r = r0 + 8k ----
#pragma unroll
    for (int k = 0; k < 8; ++k) {
        const int row = r0 + 8 * k;
        const float m = (float)row;
        const float x = phi * m;                 // exact: 12-bit phi x int<64
        const float fr = x - floorf(x);
        float rev = fmaf(plo, m, fr);
        rev -= floorf(rev);                      // [0,1) revolutions
        const float ev = exp2f(re2 * m);
        const float zr = ev * __builtin_amdgcn_cosf(rev);
        const float zi = ev * __builtin_amdgcn_sinf(rev);

        const unsigned int ur = fbits(zr), ui = fbits(zi);
        const unsigned int hp = (ur >> 16) | (ui & 0xFFFF0000u);
        const float rl = zr - bitsf(ur & 0xFFFF0000u);
        const float il = zi - bitsf(ui & 0xFFFF0000u);
        const unsigned int lp = (fbits(rl) >> 16) | (fbits(il) & 0xFFFF0000u);
        *(unsigned int*)&sAh[row][2 * n] = hp;
        *(unsigned int*)&sAl[row][2 * n] = lp;
    }

    // ---- B-table: lhs * z^{64q}, q = r0 + 8k, with 2/-2 folded ----
#pragma unroll
    for (int k = 0; k < 8; ++k) {
        const int row = r0 + 8 * k;
        const float m = (float)(row * 64);       // <= 4032
        const float x = phi * m;                 // exact: phi*m < 2^24
        const float fr = x - floorf(x);
        float rev = fmaf(plo, m, fr);
        rev -= floorf(rev);
        const float ev = exp2f(re2 * m);
        const float zr = ev * __builtin_amdgcn_cosf(rev);
        const float zi = ev * __builtin_amdgcn_sinf(rev);

        const float br = 2.0f * (lr * zr - li * zi);    //  2*Re(lhs*z^{64q})
        const float bi = -2.0f * (lr * zi + li * zr);   // -2*Im(lhs*z^{64q})

        const unsigned int ur = fbits(br), ui = fbits(bi);
        const unsigned int hp = (ur >> 16) | (ui & 0xFFFF0000u);
        const float rl = br - bitsf(ur & 0xFFFF0000u);
        const float il = bi - bitsf(ui & 0xFFFF0000u);
        const unsigned int lp = (fbits(rl) >> 16) | (fbits(il) & 0xFFFF0000u);
        *(unsigned int*)&sBh[row][2 * n] = hp;
        *(unsigned int*)&sBl[row][2 * n] = lp;
    }
    __syncthreads();

    // ---- MFMA: D[r][q] = sum_k A[r][k]*B[k][q]; 3 hi/lo products ----
    const int wv = tid >> 6;        // wave owns D rows r in [16wv, 16wv+16)
    const int lane = tid & 63;
    const int li16 = lane & 15;
    const int lg = lane >> 4;

    f32x4 acc[4];
#pragma unroll
    for (int tc = 0; tc < 4; ++tc) acc[tc] = (f32x4){0.f, 0.f, 0.f, 0.f};

    // s=0,1: Ah*Bh ; s=2,3: Ah*Bl ; s=4,5: Al*Bh   (kb = 0 / 32)
#pragma unroll
    for (int s = 0; s < 6; ++s) {
        const unsigned short (*Am)[LDK] = (s >= 4) ? sAl : sAh;
        const unsigned short (*Bm)[LDK] = (s == 2 || s == 3) ? sBl : sBh;
        const int ko = (s & 1) * 32 + 8 * lg;

        const bf16x8 af = *(const bf16x8*)&Am[16 * wv + li16][ko];
#pragma unroll
        for (int tc = 0; tc < 4; ++tc) {
            const bf16x8 bfr = *(const bf16x8*)&Bm[16 * tc + li16][ko];
            acc[tc] = __builtin_amdgcn_mfma_f32_16x16x32_bf16(af, bfr, acc[tc], 0, 0, 0);
        }
    }

    // ---- store: l = 64q + r; r = 16wv+4lg+reg (contiguous) , q = 16tc+li16 ----
    const int base = h * LLEN + 64 * li16 + 16 * wv + 4 * lg;
#pragma unroll
    for (int tc = 0; tc < 4; ++tc) {
        *(float4*)&out[base + 1024 * tc] =
            make_float4(acc[tc][0], acc[tc][1], acc[tc][2], acc[tc][3]);
    }
}

extern "C" void kernel_launch(void* const* d_in, const int* in_sizes, int n_in,
                              void* d_out, int out_size, void* d_ws, size_t ws_size,
                              hipStream_t stream) {
    const float* C_ri       = (const float*)d_in[0];
    const float* log_dt     = (const float*)d_in[1];
    const float* log_A_real = (const float*)d_in[2];
    const float* A_imag     = (const float*)d_in[3];
    float* out = (float*)d_out;

    s4d_kernel<<<dim3(HDIM), dim3(NT), 0, stream>>>(C_ri, log_dt, log_A_real, A_imag, out);
}

// Round 8
// 12.663 us; speedup vs baseline: 6.4695x; 1.0490x over previous
//
#include <hip/hip_runtime.h>
#include <math.h>

#define HDIM 1024
#define NH 32
#define LLEN 4096
#define NT 512
#define LDK 72   // padded k-stride (144 B, %128B=16 -> <=2-way conflicts, free)

typedef __attribute__((ext_vector_type(8))) short bf16x8;
typedef __attribute__((ext_vector_type(4))) float f32x4;

__device__ __forceinline__ unsigned int fbits(float x) { return __builtin_bit_cast(unsigned int, x); }
__device__ __forceinline__ float bitsf(unsigned int u) { return __builtin_bit_cast(float, u); }

__global__ __launch_bounds__(NT, 4) void s4d_kernel(
    const float* __restrict__ C_ri,
    const float* __restrict__ log_dt,
    const float* __restrict__ log_A_real,
    const float* __restrict__ A_imag,
    float* __restrict__ out)
{
    // A: rows r in [0,64): z^r   |   B: rows q in [0,64): (2Re,-2Im)(lhs*z^{64q})
    __shared__ unsigned short sAh[64][LDK], sAl[64][LDK];
    __shared__ unsigned short sBh[64][LDK], sBl[64][LDK];

    const int h = blockIdx.x;
    const int tid = threadIdx.x;
    const int n = tid & 31;        // this thread's mode
    const int hn = h * NH + n;
    const int r0 = tid >> 5;       // [0,16): row residue; rows r0+16k

    const float LOG2E = 1.4426950408889634f;

    // ---- per-thread setup, no libm calls ----
    const float dt = exp2f(log_dt[h] * LOG2E);
    const float Ar = -exp2f(log_A_real[hn] * LOG2E);
    const float Ai = A_imag[hn];
    const float dtAr = Ar * dt;
    const float dtAi = Ai * dt;
    const float re2 = dtAr * LOG2E;              // decay, log2 units per l

    const double sd = (double)dtAi * 0.15915494309189535;
    const double fdd = sd - floor(sd);           // exact fract(dtAi/2pi)
    const float phi = (float)(floor(fdd * 4096.0 + 0.5) * (1.0 / 4096.0));
    const float plo = (float)(fdd - (double)phi); // exact hi/lo split (rev/l)

    // lhs = C*(exp(dtA)-1)/A   (x2/-2 folded at B build)
    const float er = exp2f(re2);
    const float rv = (float)fdd;                 // revolutions for sincos
    const float cs = __builtin_amdgcn_cosf(rv);
    const float sn = __builtin_amdgcn_sinf(rv);
    const float Er = er * cs - 1.0f;
    const float Ei = er * sn;
    const float cr = C_ri[2 * hn + 0];
    const float ci = C_ri[2 * hn + 1];
    const float nr = cr * Er - ci * Ei;
    const float ni = cr * Ei + ci * Er;
    const float inv = 1.0f / (Ar * Ar + Ai * Ai);
    const float lr = (nr * Ar + ni * Ai) * inv;
    const float li = (ni * Ar - nr * Ai) * inv;

    // z^m (exact phase reduction; m integer-valued, m <= 1024)
    auto zpow = [&](float m, float& zr, float& zi) {
        const float x = phi * m;                 // exact: (j/4096)*m, j*m < 2^23
        const float fr = x - floorf(x);
        float rev = fmaf(plo, m, fr);
        rev -= floorf(rev);                      // [0,1) revolutions
        const float ev = exp2f(re2 * m);
        zr = ev * __builtin_amdgcn_cosf(rev);
        zi = ev * __builtin_amdgcn_sinf(rev);
    };

    // ---- A-table: 4 rows via chain z^{r0} * (z^16)^k ----
    {
        float zr, zi, sr, si;
        zpow((float)r0, zr, zi);
        zpow(16.0f, sr, si);
        int row = r0;
#pragma unroll
        for (int k = 0; k < 4; ++k) {
            const unsigned int urb = fbits(zr), uib = fbits(zi);
            const unsigned int hp = (urb >> 16) | (uib & 0xFFFF0000u);
            const float rl = zr - bitsf(urb & 0xFFFF0000u);
            const float il = zi - bitsf(uib & 0xFFFF0000u);
            const unsigned int lp = (fbits(rl) >> 16) | (fbits(il) & 0xFFFF0000u);
            *(unsigned int*)&sAh[row][2 * n] = hp;
            *(unsigned int*)&sAl[row][2 * n] = lp;
            const float t = zr * sr - zi * si;
            zi = zr * si + zi * sr;
            zr = t;
            row += 16;
        }
    }

    // ---- B-table: 4 rows via chain (lhs*z^{64 r0}) * (z^1024)^k ----
    {
        float zr, zi, sr, si;
        zpow((float)(64 * r0), zr, zi);
        zpow(1024.0f, sr, si);
        float ur = lr * zr - li * zi;
        float ui = lr * zi + li * zr;
        int row = r0;
#pragma unroll
        for (int k = 0; k < 4; ++k) {
            const float br = ur + ur;            //  2*Re
            const float bi = -(ui + ui);         // -2*Im
            const unsigned int urb = fbits(br), uib = fbits(bi);
            const unsigned int hp = (urb >> 16) | (uib & 0xFFFF0000u);
            const float rl = br - bitsf(urb & 0xFFFF0000u);
            const float il = bi - bitsf(uib & 0xFFFF0000u);
            const unsigned int lp = (fbits(rl) >> 16) | (fbits(il) & 0xFFFF0000u);
            *(unsigned int*)&sBh[row][2 * n] = hp;
            *(unsigned int*)&sBl[row][2 * n] = lp;
            const float t = ur * sr - ui * si;
            ui = ur * si + ui * sr;
            ur = t;
            row += 16;
        }
    }
    __syncthreads();

    // ---- MFMA: 8 waves x 2 tiles; D[r][q], l = 64q + r ----
    const int wv = tid >> 6;
    const int lane = tid & 63;
    const int li16 = lane & 15;
    const int lg = lane >> 4;
    const int arow = wv & 3;                     // A row-tile
    const int tc0 = (wv >> 2) * 2;               // first of 2 B col-tiles

    f32x4 acc[2];
    acc[0] = (f32x4){0.f, 0.f, 0.f, 0.f};
    acc[1] = (f32x4){0.f, 0.f, 0.f, 0.f};

    // s=0,1: Ah*Bh ; s=2,3: Ah*Bl ; s=4,5: Al*Bh   (kb = 0 / 32)
#pragma unroll
    for (int s = 0; s < 6; ++s) {
        const unsigned short (*Am)[LDK] = (s >= 4) ? sAl : sAh;
        const unsigned short (*Bm)[LDK] = (s == 2 || s == 3) ? sBl : sBh;
        const int ko = (s & 1) * 32 + 8 * lg;
        const bf16x8 af = *(const bf16x8*)&Am[16 * arow + li16][ko];
#pragma unroll
        for (int t = 0; t < 2; ++t) {
            const bf16x8 bfr = *(const bf16x8*)&Bm[16 * (tc0 + t) + li16][ko];
            acc[t] = __builtin_amdgcn_mfma_f32_16x16x32_bf16(af, bfr, acc[t], 0, 0, 0);
        }
    }

    // ---- store: r = 16*arow+4*lg+reg contiguous -> float4 ----
    const int rr = 16 * arow + 4 * lg;
#pragma unroll
    for (int t = 0; t < 2; ++t) {
        const int q = 16 * (tc0 + t) + li16;
        *(f32x4*)&out[h * LLEN + 64 * q + rr] = acc[t];
    }
}

extern "C" void kernel_launch(void* const* d_in, const int* in_sizes, int n_in,
                              void* d_out, int out_size, void* d_ws, size_t ws_size,
                              hipStream_t stream) {
    const float* C_ri       = (const float*)d_in[0];
    const float* log_dt     = (const float*)d_in[1];
    const float* log_A_real = (const float*)d_in[2];
    const float* A_imag     = (const float*)d_in[3];
    float* out = (float*)d_out;

    s4d_kernel<<<dim3(HDIM), dim3(NT), 0, stream>>>(C_ri, log_dt, log_A_real, A_imag, out);
}

// Round 9
// 12.582 us; speedup vs baseline: 6.5108x; 1.0064x over previous
//
#include <hip/hip_runtime.h>
#include <math.h>

#define HDIM 1024
#define NH 32
#define LLEN 4096
#define NT 512
#define NBLK 512   // 2 h per block

typedef __attribute__((ext_vector_type(8))) short bf16x8;
typedef __attribute__((ext_vector_type(4))) float f32x4;

__device__ __forceinline__ unsigned int fbits(float x) { return __builtin_bit_cast(unsigned int, x); }
__device__ __forceinline__ float bitsf(unsigned int u) { return __builtin_bit_cast(float, u); }

struct Setup { float lr, li, re2, phi, plo; };

__device__ __forceinline__ Setup make_setup(const float* __restrict__ C_ri,
                                            const float* __restrict__ log_dt,
                                            const float* __restrict__ log_A_real,
                                            const float* __restrict__ A_imag,
                                            int h, int n) {
    const int hn = h * NH + n;
    const float LOG2E = 1.4426950408889634f;
    const float dt = exp2f(log_dt[h] * LOG2E);
    const float Ar = -exp2f(log_A_real[hn] * LOG2E);
    const float Ai = A_imag[hn];
    const float dtAr = Ar * dt;
    const float dtAi = Ai * dt;

    Setup s;
    s.re2 = dtAr * LOG2E;                          // decay, log2 units per l
    const double sd = (double)dtAi * 0.15915494309189535;
    const double fdd = sd - floor(sd);             // exact fract(dtAi/2pi)
    s.phi = (float)(floor(fdd * 4096.0 + 0.5) * (1.0 / 4096.0));
    s.plo = (float)(fdd - (double)s.phi);          // exact hi/lo split (rev/l)

    // lhs = C*(exp(dtA)-1)/A   (x2/-2 folded at B build)
    const float er = exp2f(s.re2);
    const float rv = (float)fdd;
    const float cs = __builtin_amdgcn_cosf(rv);
    const float sn = __builtin_amdgcn_sinf(rv);
    const float Er = er * cs - 1.0f;
    const float Ei = er * sn;
    const float cr = C_ri[2 * hn + 0];
    const float ci = C_ri[2 * hn + 1];
    const float nr = cr * Er - ci * Ei;
    const float ni = cr * Ei + ci * Er;
    const float inv = 1.0f / (Ar * Ar + Ai * Ai);
    s.lr = (nr * Ar + ni * Ai) * inv;
    s.li = (ni * Ar - nr * Ai) * inv;
    return s;
}

// tables T[tab][64][64] bf16, tab: 0=Ah 1=Al 2=Bh 3=Bl
// swizzle: 16B granule g at row -> g ^ (row&7)  (dword col c -> c ^ ((row&7)<<2))
__device__ __forceinline__ void build_h(const Setup& s, int n, int r0,
                                        unsigned short (*T)[64][64]) {
    auto zpow = [&](float m, float& zr, float& zi) {
        const float x = s.phi * m;                 // exact: 12-bit phi x int
        const float fr = x - floorf(x);
        float rev = fmaf(s.plo, m, fr);
        rev -= floorf(rev);                        // [0,1) revolutions
        const float ev = exp2f(s.re2 * m);
        zr = ev * __builtin_amdgcn_cosf(rev);
        zi = ev * __builtin_amdgcn_sinf(rev);
    };
    auto put = [&](int tab, int row, float vr, float vi) {
        const unsigned ur = fbits(vr), ui = fbits(vi);
        const unsigned hp = (ur >> 16) | (ui & 0xFFFF0000u);
        const float rl = vr - bitsf(ur & 0xFFFF0000u);
        const float il = vi - bitsf(ui & 0xFFFF0000u);
        const unsigned lp = (fbits(rl) >> 16) | (fbits(il) & 0xFFFF0000u);
        const int c = n ^ ((row & 7) << 2);
        ((unsigned*)T[tab][row])[c] = hp;
        ((unsigned*)T[tab + 1][row])[c] = lp;
    };

    // A-table: z^row, rows r0+16k, via chain z^{r0} * (z^16)^k
    {
        float zr, zi, sr, si;
        zpow((float)r0, zr, zi);
        zpow(16.0f, sr, si);
        int row = r0;
#pragma unroll
        for (int k = 0; k < 4; ++k) {
            put(0, row, zr, zi);
            const float t = zr * sr - zi * si;
            zi = zr * si + zi * sr;
            zr = t;
            row += 16;
        }
    }
    // B-table: (2Re,-2Im)(lhs*z^{64 row}), via chain (lhs*z^{64 r0}) * (z^1024)^k
    {
        float zr, zi, sr, si;
        zpow((float)(64 * r0), zr, zi);
        zpow(1024.0f, sr, si);
        float ur = s.lr * zr - s.li * zi;
        float ui = s.lr * zi + s.li * zr;
        int row = r0;
#pragma unroll
        for (int k = 0; k < 4; ++k) {
            put(2, row, ur + ur, -(ui + ui));
            const float t = ur * sr - ui * si;
            ui = ur * si + ui * sr;
            ur = t;
            row += 16;
        }
    }
}

__device__ __forceinline__ void gemm_store(const unsigned short (*T)[64][64],
                                           int tid, float* __restrict__ outh) {
    const int lane = tid & 63;
    const int wv = tid >> 6;
    const int li16 = lane & 15;
    const int lg = lane >> 4;
    const int arow = wv & 3;
    const int tc0 = (wv >> 2) * 2;

    f32x4 acc0 = (f32x4){0.f, 0.f, 0.f, 0.f};
    f32x4 acc1 = (f32x4){0.f, 0.f, 0.f, 0.f};

    const int rowA = 16 * arow + li16;
    const int rowB0 = 16 * tc0 + li16;
    const int rowB1 = rowB0 + 16;

    // st=0,1: Ah*Bh ; st=2,3: Ah*Bl ; st=4,5: Al*Bh  (k-half = st&1)
#pragma unroll
    for (int st = 0; st < 6; ++st) {
        const int tabA = (st >= 4) ? 1 : 0;
        const int tabB = (st == 2 || st == 3) ? 3 : 2;
        const int j = 4 * (st & 1) + lg;           // 16B granule index
        const bf16x8 af = *(const bf16x8*)&T[tabA][rowA][8 * (j ^ (rowA & 7))];
        const bf16x8 b0 = *(const bf16x8*)&T[tabB][rowB0][8 * (j ^ (rowB0 & 7))];
        const bf16x8 b1 = *(const bf16x8*)&T[tabB][rowB1][8 * (j ^ (rowB1 & 7))];
        acc0 = __builtin_amdgcn_mfma_f32_16x16x32_bf16(af, b0, acc0, 0, 0, 0);
        acc1 = __builtin_amdgcn_mfma_f32_16x16x32_bf16(af, b1, acc1, 0, 0, 0);
    }

    // l = 64q + r; r = 16*arow+4*lg+reg contiguous -> float4 stores
    const int rr = 16 * arow + 4 * lg;
    *(f32x4*)&outh[64 * (16 * tc0 + li16) + rr] = acc0;
    *(f32x4*)&outh[64 * (16 * tc0 + 16 + li16) + rr] = acc1;
}

__global__ __launch_bounds__(NT, 4) void s4d_kernel(
    const float* __restrict__ C_ri,
    const float* __restrict__ log_dt,
    const float* __restrict__ log_A_real,
    const float* __restrict__ A_imag,
    float* __restrict__ out)
{
    __shared__ unsigned short sT[2][4][64][64];    // 64 KB: double-buffered

    const int tid = threadIdx.x;
    const int n = tid & 31;
    const int r0 = tid >> 5;
    const int h0 = blockIdx.x;
    const int h1 = blockIdx.x + NBLK;

    // both setups up front: input loads + f64 chains overlap
    const Setup s0 = make_setup(C_ri, log_dt, log_A_real, A_imag, h0, n);
    const Setup s1 = make_setup(C_ri, log_dt, log_A_real, A_imag, h1, n);

    build_h(s0, n, r0, sT[0]);
    __syncthreads();
    gemm_store(sT[0], tid, out + h0 * LLEN);       // reads buf0, stores flow
    build_h(s1, n, r0, sT[1]);                     // writes buf1 (no conflict)
    __syncthreads();
    gemm_store(sT[1], tid, out + h1 * LLEN);
}

extern "C" void kernel_launch(void* const* d_in, const int* in_sizes, int n_in,
                              void* d_out, int out_size, void* d_ws, size_t ws_size,
                              hipStream_t stream) {
    const float* C_ri       = (const float*)d_in[0];
    const float* log_dt     = (const float*)d_in[1];
    const float* log_A_real = (const float*)d_in[2];
    const float* A_imag     = (const float*)d_in[3];
    float* out = (float*)d_out;

    s4d_kernel<<<dim3(NBLK), dim3(NT), 0, stream>>>(C_ri, log_dt, log_A_real, A_imag, out);
}